// Round 16
// baseline (161.167 us; speedup 1.0000x reference)
//
#include <hip/hip_runtime.h>
#include <hip/hip_fp16.h>
#include <stdint.h>

#define NCTX 5952
#define NHEAD 16
#define NABLK 372          // NCTX/16 16-row blocks
#define NWBLK 256          // 4096/16

typedef _Float16 f16x8 __attribute__((ext_vector_type(8)));
typedef _Float16 f16x4 __attribute__((ext_vector_type(4)));
typedef float    f32x4 __attribute__((ext_vector_type(4)));

typedef const __attribute__((address_space(1))) void* gp1;
typedef __attribute__((address_space(3))) void* lp3;

__device__ __forceinline__ f32x4 mfma16(f16x8 a, f16x8 b, f32x4 c) {
    return __builtin_amdgcn_mfma_f32_16x16x32_f16(a, b, c, 0, 0, 0);
}

// s_barrier alone is NOT a compiler fence (R12 lesson): pin with sched_barrier.
#define SBAR() do { __builtin_amdgcn_sched_barrier(0); \
                    __builtin_amdgcn_s_barrier();      \
                    __builtin_amdgcn_sched_barrier(0); } while (0)

// per-seq tables: lengths {512,576,640,704,768,832,896,1024}
__device__ const int kQT[9]    = {0, 4, 9, 14, 20, 26, 33, 40, 48};
__device__ const int kBASE8[8] = {0, 512, 1088, 1728, 2432, 3200, 4032, 4928};
__device__ const int kLEN[8]   = {512, 576, 640, 704, 768, 832, 896, 1024};

// ============================================================================
// Tiled staged layout (unchanged): array = [blk16][32 tsteps][1KB chunk],
// chunk = [16 rows][4 granule-slots][8 f16], granule g at slot g^((row>>1)&3).
// ============================================================================

// ---- fused pre-split: fp32 -> f16, tiled layout (R14, unchanged) ----
__global__ __launch_bounds__(256) void presplit_all(
    const float* __restrict__ x,
    const float* __restrict__ Wq, const float* __restrict__ Wk,
    const float* __restrict__ Wv, const float* __restrict__ Wo,
    _Float16* __restrict__ Ah, _Float16* __restrict__ Wh)
{
    constexpr int NAG = NABLK * 32 * 64;
    const int idx = blockIdx.x * 256 + threadIdx.x;
    const float* src;
    _Float16* dst;
    if (idx < NAG) {
        int chunk = idx >> 6, within = idx & 63;
        int t = chunk & 31, b = chunk >> 5;
        int rb = within >> 2, go = within & 3;
        int r = b * 16 + rb;
        int g = go ^ ((r >> 1) & 3);
        src = x + (size_t)r * 1024 + t * 32 + g * 8;
        dst = Ah + (size_t)idx * 8;
    } else {
        int i2 = idx - NAG;
        int chunk = i2 >> 6, within = i2 & 63;
        int t = chunk & 31, b = chunk >> 5;
        int rb = within >> 2, go = within & 3;
        int n = b * 16 + rb;
        int g = go ^ ((n >> 1) & 3);
        const float* s = (n < 1024) ? Wq : (n < 2048) ? Wk : (n < 3072) ? Wv : Wo;
        src = s + (size_t)(n & 1023) * 1024 + t * 32 + g * 8;
        dst = Wh + (size_t)i2 * 8;
    }
    f32x4 v0 = *(const f32x4*)src;
    f32x4 v1 = *(const f32x4*)(src + 4);
    f16x8 hv;
    #pragma unroll
    for (int e = 0; e < 4; ++e) { hv[e] = (_Float16)v0[e]; hv[4 + e] = (_Float16)v1[e]; }
    *(f16x8*)dst = hv;
}

// ---- single-f16 GEMM: C = A*B^T (fp32 accum), K=1024, BK=64, 16 iters ----
// (R14 carrier, unchanged — best measured GEMM: 2 LDS bufs, depth-1 prefetch,
// one fenced barrier per BK=64 iteration.)
template <int MODE>
__global__ __launch_bounds__(512) void gemm1p(
    const _Float16* __restrict__ Ag, const _Float16* __restrict__ Wg,
    const float* __restrict__ bq, const float* __restrict__ bv, const float* __restrict__ bo,
    _Float16* __restrict__ qh, _Float16* __restrict__ kh, _Float16* __restrict__ vt,
    float* __restrict__ outp)
{
    constexpr int BN   = (MODE == 0) ? 384 : 128;
    constexpr int MI   = 6;
    constexpr int NF   = BN / 64;
    constexpr int TOT  = 24 + 2 * (BN / 16);
    constexpr int SPW  = TOT / 8;            // 9 / 5
    constexpr int ABP  = 24 * 1024;
    constexpr int BUF  = ABP + (BN / 16) * 2048;
    constexpr int T    = 16;
    constexpr int WB0  = (MODE == 0) ? 0 : 192;

    __shared__ __align__(16) char lds[2 * BUF];

    int bid = blockIdx.x;
    bid = (bid & 7) * 31 + (bid >> 3);
    const int mt = bid % 31, nt = bid / 31;
    const int m0 = mt * 192, n0 = nt * BN;
    const int tid = threadIdx.x;
    const int w = tid >> 6, l = tid & 63;
    const int ls = l >> 4, lq = l & 15;
    const int wm = w >> 2, wn = w & 3;

    const char* sbase[SPW];
    int ldst[SPW];
    #pragma unroll
    for (int s = 0; s < SPW; ++s) {
        int c = w * SPW + s;
        if (c < 24) {
            int f = c >> 1, sub = c & 1;
            sbase[s] = (const char*)Ag + (size_t)(m0 / 16 + f) * 32768 + sub * 1024;
        } else {
            int cB = c - 24, f = cB >> 1, sub = cB & 1;
            sbase[s] = (const char*)Wg + (size_t)(WB0 + n0 / 16 + f) * 32768 + sub * 1024;
        }
        ldst[s] = c * 1024;
    }
    const int l16 = l * 16;
    auto STG = [&](int buf, int t2) {
        #pragma unroll
        for (int s = 0; s < SPW; ++s)
            __builtin_amdgcn_global_load_lds((gp1)(sbase[s] + (size_t)t2 * 2048 + l16),
                                             (lp3)(lds + buf * BUF + ldst[s]), 16, 0, 0);
    };

    int aoA[MI], aoB[NF];
    #pragma unroll
    for (int i = 0; i < MI; ++i) {
        int r = wm * 96 + i * 16 + lq;
        aoA[i] = (r >> 4) * 2048 + (r & 15) * 64 + ((ls ^ ((r >> 1) & 3)) << 4);
    }
    #pragma unroll
    for (int j = 0; j < NF; ++j) {
        int r = wn * (16 * NF) + j * 16 + lq;
        aoB[j] = ABP + (r >> 4) * 2048 + (r & 15) * 64 + ((ls ^ ((r >> 1) & 3)) << 4);
    }

    f32x4 acc[MI][NF] = {};

    STG(0, 0);
    asm volatile("s_waitcnt vmcnt(0)" ::: "memory");
    SBAR();

    #pragma unroll 1
    for (int t = 0; t < T; ++t) {
        const char* cbp = lds + (t & 1) * BUF;
        if (t + 1 < T) STG((t + 1) & 1, t + 1);

        #pragma unroll
        for (int kc = 0; kc < 2; ++kc) {
            f16x8 ah[MI], b[NF];
            #pragma unroll
            for (int i = 0; i < MI; ++i) ah[i] = *(const f16x8*)(cbp + aoA[i] + kc * 1024);
            #pragma unroll
            for (int j = 0; j < NF; ++j) b[j] = *(const f16x8*)(cbp + aoB[j] + kc * 1024);
            __builtin_amdgcn_s_setprio(1);
            #pragma unroll
            for (int i = 0; i < MI; ++i)
                #pragma unroll
                for (int j = 0; j < NF; ++j)
                    acc[i][j] = mfma16(ah[i], b[j], acc[i][j]);
            __builtin_amdgcn_s_setprio(0);
        }

        asm volatile("s_waitcnt vmcnt(0) lgkmcnt(0)" ::: "memory");
        SBAR();
    }

    #pragma unroll
    for (int i = 0; i < MI; ++i)
        #pragma unroll
        for (int j = 0; j < NF; ++j) {
            const int mb = m0 + wm * 96 + i * 16 + 4 * ls;
            const int n  = n0 + wn * (16 * NF) + j * 16 + lq;
            if (MODE == 0) {
                const int which = n >> 10, nn = n & 1023;
                const int hh = nn >> 6, dd = nn & 63;
                if (which == 2) {
                    f16x4 vv;
                    #pragma unroll
                    for (int r = 0; r < 4; ++r) vv[r] = (_Float16)(acc[i][j][r] + bv[nn]);
                    *(f16x4*)&vt[((size_t)hh * 64 + dd) * NCTX + mb] = vv;   // d-major
                } else if (which == 0) {
                    #pragma unroll
                    for (int r = 0; r < 4; ++r)
                        qh[((size_t)hh * NCTX + mb + r) * 64 + dd] = (_Float16)(acc[i][j][r] + bq[nn]);
                } else {
                    #pragma unroll
                    for (int r = 0; r < 4; ++r)
                        kh[((size_t)hh * NCTX + mb + r) * 64 + dd] = (_Float16)acc[i][j][r];
                }
            } else {
                #pragma unroll
                for (int r = 0; r < 4; ++r)
                    outp[(size_t)(mb + r) * 1024 + n] = acc[i][j][r] + bo[n];
            }
        }
}

// ---- flash attention (no-max): barrier-free direct-L2 with reg prefetch ----
// K/V per head-seq <= 512KB (L2-resident): no LDS staging, no s_barrier.
// K-frags ping-pong prefetched one kv-step ahead (named sets, static idx);
// V-frags issued at step top so L2 latency drains under softmax+P roundtrip.
// P stays wave-private LDS; tail waves early-exit (legal: zero barriers).
__global__ __launch_bounds__(256) void attn_kernel(
    const _Float16* __restrict__ qh, const _Float16* __restrict__ kh,
    const _Float16* __restrict__ vt,
    _Float16* __restrict__ Ahc)
{
    __shared__ alignas(16) _Float16 P[4][2][16][64];
    const int bid = blockIdx.x;
    const int hd = bid & 15, t = bid >> 4;
    int b = 0;
    while (t >= kQT[b + 1]) ++b;
    const int kbase = kBASE8[b];
    const int L = kLEN[b];
    const int w = threadIdx.x >> 6, l = threadIdx.x & 63;
    const int ls = l >> 4, lq = l & 15;
    const int q0l = (t - kQT[b]) * 128 + w * 32;
    if (q0l >= L) return;            // no barriers below: safe early-exit
    const int q0 = kbase + q0l;

    f16x8 qf[2][2];
    #pragma unroll
    for (int qg = 0; qg < 2; ++qg) {
        const _Float16* qp = qh + ((size_t)hd * NCTX + q0 + qg * 16 + lq) * 64 + ls * 8;
        qf[qg][0] = *(const f16x8*)qp;
        qf[qg][1] = *(const f16x8*)(qp + 32);
    }
    // per-lane K/V bases (R9-verified addressing)
    const _Float16* kpl = kh + ((size_t)hd * NCTX + kbase + lq) * 64 + ls * 8;
    const _Float16* vpl = vt + ((size_t)hd * 64 + lq) * NCTX + kbase + ls * 8;

    f32x4 acc[2][4] = {};
    float lsum[2] = {0.f, 0.f};
    const int nst = L >> 6;

    f16x8 kA[8], kB[8];
    #pragma unroll
    for (int g = 0; g < 4; ++g) {
        kA[2 * g]     = *(const f16x8*)(kpl + (size_t)(g * 16) * 64);
        kA[2 * g + 1] = *(const f16x8*)(kpl + (size_t)(g * 16) * 64 + 32);
    }

    auto STEP = [&](int tt, f16x8 (&kC)[8], f16x8 (&kN)[8]) {
        // prefetch next step's K (fully hidden under this step's compute)
        if (tt + 1 < nst) {
            #pragma unroll
            for (int g = 0; g < 4; ++g) {
                kN[2 * g]     = *(const f16x8*)(kpl + (size_t)((tt + 1) * 64 + g * 16) * 64);
                kN[2 * g + 1] = *(const f16x8*)(kpl + (size_t)((tt + 1) * 64 + g * 16) * 64 + 32);
            }
        }
        // V for this step: issued now, consumed after softmax (~200cyc gap)
        f16x8 vC[8];
        #pragma unroll
        for (int dg = 0; dg < 4; ++dg)
            #pragma unroll
            for (int c = 0; c < 2; ++c)
                vC[dg * 2 + c] = *(const f16x8*)(vpl + (size_t)(dg * 16) * NCTX + tt * 64 + c * 32);

        // S^T = K.Q : row = key, col = q = lane&15
        f32x4 s[2][4];
        __builtin_amdgcn_s_setprio(1);
        #pragma unroll
        for (int g = 0; g < 4; ++g)
            #pragma unroll
            for (int qg = 0; qg < 2; ++qg) {
                f32x4 z = {};
                z = mfma16(kC[2 * g], qf[qg][0], z);
                z = mfma16(kC[2 * g + 1], qf[qg][1], z);
                s[qg][g] = z;
            }
        __builtin_amdgcn_s_setprio(0);
        // softmax (no-max: scores bounded); P via wave-private LDS
        #pragma unroll
        for (int qg = 0; qg < 2; ++qg) {
            float tsum = 0.f;
            #pragma unroll
            for (int g = 0; g < 4; ++g) {
                f16x4 ph;
                #pragma unroll
                for (int r = 0; r < 4; ++r) {
                    float pv = __expf(s[qg][g][r] * 0.125f);
                    tsum += pv;
                    ph[r] = (_Float16)pv;
                }
                int gi = 2 * g + (ls >> 1);
                *(f16x4*)&P[w][qg][lq][(((gi ^ (lq & 7)) << 3) | ((ls & 1) << 2))] = ph;
            }
            tsum += __shfl_xor(tsum, 16, 64);
            tsum += __shfl_xor(tsum, 32, 64);
            lsum[qg] += tsum;
        }
        // ctx^T += V^T @ P^T
        __builtin_amdgcn_s_setprio(1);
        #pragma unroll
        for (int c = 0; c < 2; ++c) {
            f16x8 pf[2];
            #pragma unroll
            for (int qg = 0; qg < 2; ++qg)
                pf[qg] = *(const f16x8*)&P[w][qg][lq][((4 * c + ls) ^ (lq & 7)) << 3];
            #pragma unroll
            for (int dg = 0; dg < 4; ++dg)
                #pragma unroll
                for (int qg = 0; qg < 2; ++qg)
                    acc[qg][dg] = mfma16(vC[dg * 2 + c], pf[qg], acc[qg][dg]);
        }
        __builtin_amdgcn_s_setprio(0);
    };

    #pragma unroll 1
    for (int tt = 0; tt < nst; tt += 2) {
        STEP(tt, kA, kB);
        if (tt + 1 < nst) STEP(tt + 1, kB, kA);
    }

    // epilogue: ctx (single f16) written directly in the tiled staged layout
    #pragma unroll
    for (int qg = 0; qg < 2; ++qg) {
        const float inv = 1.f / lsum[qg];
        const int m = q0 + qg * 16 + lq;
        const int bA = m >> 4, rbA = m & 15, xr = (m >> 1) & 3;
        #pragma unroll
        for (int dg = 0; dg < 4; ++dg) {
            const int k  = hd * 64 + dg * 16 + 4 * ls;
            const int tK = k >> 5;
            const int gs = ((k >> 3) & 3) ^ xr;
            const int e  = k & 7;
            f16x4 ch;
            #pragma unroll
            for (int r = 0; r < 4; ++r) ch[r] = (_Float16)(acc[qg][dg][r] * inv);
            *(f16x4*)((char*)Ahc + ((size_t)(bA * 32 + tK)) * 1024 + rbA * 64 + gs * 16 + e * 2) = ch;
        }
    }
}

extern "C" void kernel_launch(void* const* d_in, const int* in_sizes, int n_in,
                              void* d_out, int out_size, void* d_ws, size_t ws_size,
                              hipStream_t stream)
{
    const float* x  = (const float*)d_in[0];
    const float* Wq = (const float*)d_in[1];
    const float* bq = (const float*)d_in[2];
    const float* Wk = (const float*)d_in[3];
    const float* Wv = (const float*)d_in[4];
    const float* bv = (const float*)d_in[5];
    const float* Wo = (const float*)d_in[6];
    const float* bo = (const float*)d_in[7];
    float* out = (float*)d_out;

    char* p = (char*)d_ws;
    _Float16* Ah  = (_Float16*)p; p += (size_t)NCTX * 1024 * 2;   // tiled
    _Float16* Wh  = (_Float16*)p; p += (size_t)4096 * 1024 * 2;   // tiled
    _Float16* qh  = (_Float16*)p; p += (size_t)NHEAD * NCTX * 64 * 2;
    _Float16* kh  = (_Float16*)p; p += (size_t)NHEAD * NCTX * 64 * 2;
    _Float16* vt  = (_Float16*)p; p += (size_t)NHEAD * NCTX * 64 * 2;
    _Float16* Ahc = (_Float16*)p; p += (size_t)NCTX * 1024 * 2;   // tiled

    presplit_all<<<dim3((NABLK * 32 * 64 + NWBLK * 32 * 64) / 256), 256, 0, stream>>>(
        x, Wq, Wk, Wv, Wo, Ah, Wh);
    gemm1p<0><<<dim3(248), 512, 0, stream>>>(Ah, Wh, bq, bv, nullptr,
                                             qh, kh, vt, nullptr);
    attn_kernel<<<dim3(48 * 16), 256, 0, stream>>>(qh, kh, vt, Ahc);
    gemm1p<1><<<dim3(248), 512, 0, stream>>>(Ahc, Wh, nullptr, nullptr, bo,
                                             nullptr, nullptr, nullptr, out);
}

// Round 17
// 136.925 us; speedup vs baseline: 1.1770x; 1.1770x over previous
//
#include <hip/hip_runtime.h>
#include <hip/hip_fp16.h>
#include <stdint.h>

#define NCTX 5952
#define NHEAD 16
#define NABLK 372          // NCTX/16 16-row blocks
#define NWBLK 256          // 4096/16

typedef _Float16 f16x8 __attribute__((ext_vector_type(8)));
typedef _Float16 f16x4 __attribute__((ext_vector_type(4)));
typedef float    f32x4 __attribute__((ext_vector_type(4)));

typedef const __attribute__((address_space(1))) void* gp1;
typedef __attribute__((address_space(3))) void* lp3;

__device__ __forceinline__ f32x4 mfma16(f16x8 a, f16x8 b, f32x4 c) {
    return __builtin_amdgcn_mfma_f32_16x16x32_f16(a, b, c, 0, 0, 0);
}

// s_barrier alone is NOT a compiler fence (R12 lesson): pin with sched_barrier.
#define SBAR() do { __builtin_amdgcn_sched_barrier(0); \
                    __builtin_amdgcn_s_barrier();      \
                    __builtin_amdgcn_sched_barrier(0); } while (0)

// per-seq tables: lengths {512,576,640,704,768,832,896,1024}
__device__ const int kQT[9]    = {0, 2, 5, 8, 11, 14, 18, 22, 26};  // cum 256-row q-tiles
__device__ const int kBASE8[8] = {0, 512, 1088, 1728, 2432, 3200, 4032, 4928};
__device__ const int kLEN[8]   = {512, 576, 640, 704, 768, 832, 896, 1024};

// ============================================================================
// Tiled staged layout (unchanged): array = [blk16][32 tsteps][1KB chunk],
// chunk = [16 rows][4 granule-slots][8 f16], granule g at slot g^((row>>1)&3).
// ============================================================================

// ---- fused pre-split: fp32 -> f16, tiled layout (R14, unchanged) ----
__global__ __launch_bounds__(256) void presplit_all(
    const float* __restrict__ x,
    const float* __restrict__ Wq, const float* __restrict__ Wk,
    const float* __restrict__ Wv, const float* __restrict__ Wo,
    _Float16* __restrict__ Ah, _Float16* __restrict__ Wh)
{
    constexpr int NAG = NABLK * 32 * 64;
    const int idx = blockIdx.x * 256 + threadIdx.x;
    const float* src;
    _Float16* dst;
    if (idx < NAG) {
        int chunk = idx >> 6, within = idx & 63;
        int t = chunk & 31, b = chunk >> 5;
        int rb = within >> 2, go = within & 3;
        int r = b * 16 + rb;
        int g = go ^ ((r >> 1) & 3);
        src = x + (size_t)r * 1024 + t * 32 + g * 8;
        dst = Ah + (size_t)idx * 8;
    } else {
        int i2 = idx - NAG;
        int chunk = i2 >> 6, within = i2 & 63;
        int t = chunk & 31, b = chunk >> 5;
        int rb = within >> 2, go = within & 3;
        int n = b * 16 + rb;
        int g = go ^ ((n >> 1) & 3);
        const float* s = (n < 1024) ? Wq : (n < 2048) ? Wk : (n < 3072) ? Wv : Wo;
        src = s + (size_t)(n & 1023) * 1024 + t * 32 + g * 8;
        dst = Wh + (size_t)i2 * 8;
    }
    f32x4 v0 = *(const f32x4*)src;
    f32x4 v1 = *(const f32x4*)(src + 4);
    f16x8 hv;
    #pragma unroll
    for (int e = 0; e < 4; ++e) { hv[e] = (_Float16)v0[e]; hv[4 + e] = (_Float16)v1[e]; }
    *(f16x8*)dst = hv;
}

// ---- single-f16 GEMM: C = A*B^T (fp32 accum), K=1024, BK=64, 16 iters ----
// (R14 carrier, unchanged — best measured GEMM.)
template <int MODE>
__global__ __launch_bounds__(512) void gemm1p(
    const _Float16* __restrict__ Ag, const _Float16* __restrict__ Wg,
    const float* __restrict__ bq, const float* __restrict__ bv, const float* __restrict__ bo,
    _Float16* __restrict__ qh, _Float16* __restrict__ kh, _Float16* __restrict__ vt,
    float* __restrict__ outp)
{
    constexpr int BN   = (MODE == 0) ? 384 : 128;
    constexpr int MI   = 6;
    constexpr int NF   = BN / 64;
    constexpr int TOT  = 24 + 2 * (BN / 16);
    constexpr int SPW  = TOT / 8;            // 9 / 5
    constexpr int ABP  = 24 * 1024;
    constexpr int BUF  = ABP + (BN / 16) * 2048;
    constexpr int T    = 16;
    constexpr int WB0  = (MODE == 0) ? 0 : 192;

    __shared__ __align__(16) char lds[2 * BUF];

    int bid = blockIdx.x;
    bid = (bid & 7) * 31 + (bid >> 3);
    const int mt = bid % 31, nt = bid / 31;
    const int m0 = mt * 192, n0 = nt * BN;
    const int tid = threadIdx.x;
    const int w = tid >> 6, l = tid & 63;
    const int ls = l >> 4, lq = l & 15;
    const int wm = w >> 2, wn = w & 3;

    const char* sbase[SPW];
    int ldst[SPW];
    #pragma unroll
    for (int s = 0; s < SPW; ++s) {
        int c = w * SPW + s;
        if (c < 24) {
            int f = c >> 1, sub = c & 1;
            sbase[s] = (const char*)Ag + (size_t)(m0 / 16 + f) * 32768 + sub * 1024;
        } else {
            int cB = c - 24, f = cB >> 1, sub = cB & 1;
            sbase[s] = (const char*)Wg + (size_t)(WB0 + n0 / 16 + f) * 32768 + sub * 1024;
        }
        ldst[s] = c * 1024;
    }
    const int l16 = l * 16;
    auto STG = [&](int buf, int t2) {
        #pragma unroll
        for (int s = 0; s < SPW; ++s)
            __builtin_amdgcn_global_load_lds((gp1)(sbase[s] + (size_t)t2 * 2048 + l16),
                                             (lp3)(lds + buf * BUF + ldst[s]), 16, 0, 0);
    };

    int aoA[MI], aoB[NF];
    #pragma unroll
    for (int i = 0; i < MI; ++i) {
        int r = wm * 96 + i * 16 + lq;
        aoA[i] = (r >> 4) * 2048 + (r & 15) * 64 + ((ls ^ ((r >> 1) & 3)) << 4);
    }
    #pragma unroll
    for (int j = 0; j < NF; ++j) {
        int r = wn * (16 * NF) + j * 16 + lq;
        aoB[j] = ABP + (r >> 4) * 2048 + (r & 15) * 64 + ((ls ^ ((r >> 1) & 3)) << 4);
    }

    f32x4 acc[MI][NF] = {};

    STG(0, 0);
    asm volatile("s_waitcnt vmcnt(0)" ::: "memory");
    SBAR();

    #pragma unroll 1
    for (int t = 0; t < T; ++t) {
        const char* cbp = lds + (t & 1) * BUF;
        if (t + 1 < T) STG((t + 1) & 1, t + 1);

        #pragma unroll
        for (int kc = 0; kc < 2; ++kc) {
            f16x8 ah[MI], b[NF];
            #pragma unroll
            for (int i = 0; i < MI; ++i) ah[i] = *(const f16x8*)(cbp + aoA[i] + kc * 1024);
            #pragma unroll
            for (int j = 0; j < NF; ++j) b[j] = *(const f16x8*)(cbp + aoB[j] + kc * 1024);
            __builtin_amdgcn_s_setprio(1);
            #pragma unroll
            for (int i = 0; i < MI; ++i)
                #pragma unroll
                for (int j = 0; j < NF; ++j)
                    acc[i][j] = mfma16(ah[i], b[j], acc[i][j]);
            __builtin_amdgcn_s_setprio(0);
        }

        asm volatile("s_waitcnt vmcnt(0) lgkmcnt(0)" ::: "memory");
        SBAR();
    }

    #pragma unroll
    for (int i = 0; i < MI; ++i)
        #pragma unroll
        for (int j = 0; j < NF; ++j) {
            const int mb = m0 + wm * 96 + i * 16 + 4 * ls;
            const int n  = n0 + wn * (16 * NF) + j * 16 + lq;
            if (MODE == 0) {
                const int which = n >> 10, nn = n & 1023;
                const int hh = nn >> 6, dd = nn & 63;
                if (which == 2) {
                    f16x4 vv;
                    #pragma unroll
                    for (int r = 0; r < 4; ++r) vv[r] = (_Float16)(acc[i][j][r] + bv[nn]);
                    *(f16x4*)&vt[((size_t)hh * 64 + dd) * NCTX + mb] = vv;   // d-major
                } else if (which == 0) {
                    #pragma unroll
                    for (int r = 0; r < 4; ++r)
                        qh[((size_t)hh * NCTX + mb + r) * 64 + dd] = (_Float16)(acc[i][j][r] + bq[nn]);
                } else {
                    #pragma unroll
                    for (int r = 0; r < 4; ++r)
                        kh[((size_t)hh * NCTX + mb + r) * 64 + dd] = (_Float16)acc[i][j][r];
                }
            } else {
                #pragma unroll
                for (int r = 0; r < 4; ++r)
                    outp[(size_t)(mb + r) * 1024 + n] = acc[i][j][r] + bo[n];
            }
        }
}

// ---- flash attention (no-max), 4 waves x 64 q-rows per 256-row tile ----
// R14 staged structure (block-cooperative dbuf K/V, fenced barriers) with
// 2x q-rows per wave: K/V LDS reads and staging amortized over 64 MFMA/step.
// QK^T split into two 2-keygroup halves to keep live scores at s[4][2].
__global__ __launch_bounds__(256) void attn_kernel(
    const _Float16* __restrict__ qh, const _Float16* __restrict__ kh,
    const _Float16* __restrict__ vt,
    _Float16* __restrict__ Ahc)
{
    __shared__ alignas(16) _Float16 KT[2][64][64];   // [buf][key][d], granule^=(key&7)
    __shared__ alignas(16) _Float16 VT[2][64][64];   // [buf][d][key], granule^=(d&7)
    __shared__ alignas(16) _Float16 P[4][4][16][64]; // [wave][qg][q][key]
    const int bid = blockIdx.x;
    const int hd = bid & 15, t = bid >> 4;
    int b = 0;
    while (t >= kQT[b + 1]) ++b;
    const int kbase = kBASE8[b];
    const int L = kLEN[b];
    const int w = threadIdx.x >> 6, l = threadIdx.x & 63;
    const int ls = l >> 4, lq = l & 15;
    const int xm = lq & 7;
    const int q0l = (t - kQT[b]) * 256 + w * 64;
    const bool active = (q0l < L);       // 64-row waves; L % 64 == 0
    const int q0 = kbase + q0l;

    const _Float16* kb = kh + (size_t)hd * NCTX * 64;
    const _Float16* vb = vt + (size_t)hd * 64 * NCTX;

    const char* ksrc[2]; const char* vsrc[2]; int sdst[2];
    #pragma unroll
    for (int s = 0; s < 2; ++s) {
        int G = w * 128 + s * 64 + l;
        int row = G >> 3, g = G & 7;
        ksrc[s] = (const char*)(kb + ((size_t)(kbase + row)) * 64 + (size_t)((g ^ (row & 7)) * 8));
        vsrc[s] = (const char*)(vb + (size_t)row * NCTX + kbase + (size_t)((g ^ (row & 7)) * 8));
        sdst[s] = (w * 128 + s * 64) * 16;   // wave-uniform base; HW adds lane*16
    }
    auto STG = [&](int buf, int t2) {
        #pragma unroll
        for (int s = 0; s < 2; ++s)
            __builtin_amdgcn_global_load_lds((gp1)(ksrc[s] + (size_t)t2 * 8192),
                                             (lp3)((char*)&KT[buf][0][0] + sdst[s]), 16, 0, 0);
        #pragma unroll
        for (int s = 0; s < 2; ++s)
            __builtin_amdgcn_global_load_lds((gp1)(vsrc[s] + (size_t)t2 * 128),
                                             (lp3)((char*)&VT[buf][0][0] + sdst[s]), 16, 0, 0);
    };

    f16x8 qf[4][2];
    if (active) {
        #pragma unroll
        for (int qg = 0; qg < 4; ++qg) {
            const _Float16* qp = qh + ((size_t)hd * NCTX + q0 + qg * 16 + lq) * 64 + ls * 8;
            qf[qg][0] = *(const f16x8*)qp;
            qf[qg][1] = *(const f16x8*)(qp + 32);
        }
    }

    f32x4 acc[4][4] = {};
    float lsum[4] = {0.f, 0.f, 0.f, 0.f};
    const int nst = L >> 6;

    STG(0, 0);
    #pragma unroll 1
    for (int tt = 0; tt < nst; ++tt) {
        const int buf = tt & 1;
        if (tt + 1 < nst) {
            STG(buf ^ 1, tt + 1);
            asm volatile("s_waitcnt vmcnt(4)" ::: "memory");
        } else {
            asm volatile("s_waitcnt vmcnt(0)" ::: "memory");
        }
        SBAR();    // buf tt staged block-wide; reads pinned below

        if (active) {
            float tsum[4] = {0.f, 0.f, 0.f, 0.f};
            // QK^T + softmax in two 32-key halves (keeps live scores small)
            #pragma unroll
            for (int gh = 0; gh < 2; ++gh) {
                f32x4 s[4][2];
                __builtin_amdgcn_s_setprio(1);
                #pragma unroll
                for (int gg = 0; gg < 2; ++gg) {
                    const int g = gh * 2 + gg;
                    const char* kp = (const char*)&KT[buf][g * 16 + lq][0];
                    f16x8 kf0 = *(const f16x8*)(kp + ((ls ^ xm) * 16));
                    f16x8 kf1 = *(const f16x8*)(kp + (((ls + 4) ^ xm) * 16));
                    #pragma unroll
                    for (int qg = 0; qg < 4; ++qg) {
                        f32x4 z = {};
                        z = mfma16(kf0, qf[qg][0], z);
                        z = mfma16(kf1, qf[qg][1], z);
                        s[qg][gg] = z;   // S^T: row = key, col = q = lane&15
                    }
                }
                __builtin_amdgcn_s_setprio(0);
                #pragma unroll
                for (int qg = 0; qg < 4; ++qg)
                    #pragma unroll
                    for (int gg = 0; gg < 2; ++gg) {
                        const int g = gh * 2 + gg;
                        f16x4 ph;
                        #pragma unroll
                        for (int r = 0; r < 4; ++r) {
                            float pv = __expf(s[qg][gg][r] * 0.125f);
                            tsum[qg] += pv;
                            ph[r] = (_Float16)pv;
                        }
                        int gi = 2 * g + (ls >> 1);
                        *(f16x4*)&P[w][qg][lq][(((gi ^ (lq & 7)) << 3) | ((ls & 1) << 2))] = ph;
                    }
            }
            #pragma unroll
            for (int qg = 0; qg < 4; ++qg) {
                float ts = tsum[qg];
                ts += __shfl_xor(ts, 16, 64);
                ts += __shfl_xor(ts, 32, 64);
                lsum[qg] += ts;
            }
            // ctx^T += V^T @ P^T
            __builtin_amdgcn_s_setprio(1);
            #pragma unroll
            for (int c = 0; c < 2; ++c) {
                f16x8 pf[4];
                #pragma unroll
                for (int qg = 0; qg < 4; ++qg)
                    pf[qg] = *(const f16x8*)&P[w][qg][lq][((4 * c + ls) ^ (lq & 7)) << 3];
                #pragma unroll
                for (int dg = 0; dg < 4; ++dg) {
                    const char* vp = (const char*)&VT[buf][dg * 16 + lq][0];
                    f16x8 vf = *(const f16x8*)(vp + (((c * 4 + ls) ^ xm) * 16));
                    #pragma unroll
                    for (int qg = 0; qg < 4; ++qg)
                        acc[qg][dg] = mfma16(vf, pf[qg], acc[qg][dg]);
                }
            }
            __builtin_amdgcn_s_setprio(0);
        }

        // everyone's LDS reads of buf done before next staging overwrites it
        asm volatile("s_waitcnt lgkmcnt(0)" ::: "memory");
        SBAR();    // next iteration's STG pinned below
    }

    if (active) {
        #pragma unroll
        for (int qg = 0; qg < 4; ++qg) {
            const float inv = 1.f / lsum[qg];
            const int m = q0 + qg * 16 + lq;     // ctx^T col = q = lane&15
            const int bA = m >> 4, rbA = m & 15, xr = (m >> 1) & 3;
            #pragma unroll
            for (int dg = 0; dg < 4; ++dg) {
                const int k  = hd * 64 + dg * 16 + 4 * ls;
                const int tK = k >> 5;
                const int gs = ((k >> 3) & 3) ^ xr;
                const int e  = k & 7;
                f16x4 ch;
                #pragma unroll
                for (int r = 0; r < 4; ++r) ch[r] = (_Float16)(acc[qg][dg][r] * inv);
                *(f16x4*)((char*)Ahc + ((size_t)(bA * 32 + tK)) * 1024 + rbA * 64 + gs * 16 + e * 2) = ch;
            }
        }
    }
}

extern "C" void kernel_launch(void* const* d_in, const int* in_sizes, int n_in,
                              void* d_out, int out_size, void* d_ws, size_t ws_size,
                              hipStream_t stream)
{
    const float* x  = (const float*)d_in[0];
    const float* Wq = (const float*)d_in[1];
    const float* bq = (const float*)d_in[2];
    const float* Wk = (const float*)d_in[3];
    const float* Wv = (const float*)d_in[4];
    const float* bv = (const float*)d_in[5];
    const float* Wo = (const float*)d_in[6];
    const float* bo = (const float*)d_in[7];
    float* out = (float*)d_out;

    char* p = (char*)d_ws;
    _Float16* Ah  = (_Float16*)p; p += (size_t)NCTX * 1024 * 2;   // tiled
    _Float16* Wh  = (_Float16*)p; p += (size_t)4096 * 1024 * 2;   // tiled
    _Float16* qh  = (_Float16*)p; p += (size_t)NHEAD * NCTX * 64 * 2;
    _Float16* kh  = (_Float16*)p; p += (size_t)NHEAD * NCTX * 64 * 2;
    _Float16* vt  = (_Float16*)p; p += (size_t)NHEAD * NCTX * 64 * 2;
    _Float16* Ahc = (_Float16*)p; p += (size_t)NCTX * 1024 * 2;   // tiled

    presplit_all<<<dim3((NABLK * 32 * 64 + NWBLK * 32 * 64) / 256), 256, 0, stream>>>(
        x, Wq, Wk, Wv, Wo, Ah, Wh);
    gemm1p<0><<<dim3(248), 512, 0, stream>>>(Ah, Wh, bq, bv, nullptr,
                                             qh, kh, vt, nullptr);
    attn_kernel<<<dim3(26 * 16), 256, 0, stream>>>(qh, kh, vt, Ahc);
    gemm1p<1><<<dim3(248), 512, 0, stream>>>(Ahc, Wh, nullptr, nullptr, bo,
                                             nullptr, nullptr, nullptr, out);
}

// Round 18
// 126.072 us; speedup vs baseline: 1.2784x; 1.0861x over previous
//
#include <hip/hip_runtime.h>
#include <hip/hip_fp16.h>
#include <stdint.h>

#define NCTX 5952
#define NHEAD 16
#define NABLK 372          // NCTX/16 16-row blocks
#define NWBLK 256          // 4096/16

typedef _Float16 f16x8 __attribute__((ext_vector_type(8)));
typedef _Float16 f16x4 __attribute__((ext_vector_type(4)));
typedef float    f32x4 __attribute__((ext_vector_type(4)));

typedef const __attribute__((address_space(1))) void* gp1;
typedef __attribute__((address_space(3))) void* lp3;

__device__ __forceinline__ f32x4 mfma16(f16x8 a, f16x8 b, f32x4 c) {
    return __builtin_amdgcn_mfma_f32_16x16x32_f16(a, b, c, 0, 0, 0);
}

// s_barrier alone is NOT a compiler fence (R12 lesson): pin with sched_barrier.
#define SBAR() do { __builtin_amdgcn_sched_barrier(0); \
                    __builtin_amdgcn_s_barrier();      \
                    __builtin_amdgcn_sched_barrier(0); } while (0)

// per-seq tables: lengths {512,576,640,704,768,832,896,1024}
__device__ const int kQT[9]    = {0, 4, 9, 14, 20, 26, 33, 40, 48}; // cum 128-row q-tiles
__device__ const int kBASE8[8] = {0, 512, 1088, 1728, 2432, 3200, 4032, 4928};
__device__ const int kLEN[8]   = {512, 576, 640, 704, 768, 832, 896, 1024};

// ============================================================================
// Tiled staged layout: array = [blk16][32 tsteps][1KB chunk], where a chunk =
// [16 rows][4 granule-slots][8 f16] with granule g stored at slot g^((row>>1)&3).
// GEMM stages a chunk with ONE linear global_load_lds (lane l <- base + l*16);
// the LDS image equals the proven 0-conflict swizzled tile.
// ============================================================================

// ---- fused pre-split: fp32 -> f16, tiled layout ----
__global__ __launch_bounds__(256) void presplit_all(
    const float* __restrict__ x,
    const float* __restrict__ Wq, const float* __restrict__ Wk,
    const float* __restrict__ Wv, const float* __restrict__ Wo,
    _Float16* __restrict__ Ah, _Float16* __restrict__ Wh)
{
    constexpr int NAG = NABLK * 32 * 64;
    const int idx = blockIdx.x * 256 + threadIdx.x;
    const float* src;
    _Float16* dst;
    if (idx < NAG) {
        int chunk = idx >> 6, within = idx & 63;
        int t = chunk & 31, b = chunk >> 5;
        int rb = within >> 2, go = within & 3;
        int r = b * 16 + rb;
        int g = go ^ ((r >> 1) & 3);
        src = x + (size_t)r * 1024 + t * 32 + g * 8;
        dst = Ah + (size_t)idx * 8;
    } else {
        int i2 = idx - NAG;
        int chunk = i2 >> 6, within = i2 & 63;
        int t = chunk & 31, b = chunk >> 5;
        int rb = within >> 2, go = within & 3;
        int n = b * 16 + rb;
        int g = go ^ ((n >> 1) & 3);
        const float* s = (n < 1024) ? Wq : (n < 2048) ? Wk : (n < 3072) ? Wv : Wo;
        src = s + (size_t)(n & 1023) * 1024 + t * 32 + g * 8;
        dst = Wh + (size_t)i2 * 8;
    }
    f32x4 v0 = *(const f32x4*)src;
    f32x4 v1 = *(const f32x4*)(src + 4);
    f16x8 hv;
    #pragma unroll
    for (int e = 0; e < 4; ++e) { hv[e] = (_Float16)v0[e]; hv[4 + e] = (_Float16)v1[e]; }
    *(f16x8*)dst = hv;
}

// ---- single-f16 GEMM: C = A*B^T (fp32 accum), K=1024, BK=64, 16 iters ----
// 2 LDS buffers, depth-1 prefetch, one fenced barrier per BK=64 iteration.
template <int MODE>
__global__ __launch_bounds__(512) void gemm1p(
    const _Float16* __restrict__ Ag, const _Float16* __restrict__ Wg,
    const float* __restrict__ bq, const float* __restrict__ bv, const float* __restrict__ bo,
    _Float16* __restrict__ qh, _Float16* __restrict__ kh, _Float16* __restrict__ vt,
    float* __restrict__ outp)
{
    constexpr int BN   = (MODE == 0) ? 384 : 128;
    constexpr int MI   = 6;
    constexpr int NF   = BN / 64;
    constexpr int TOT  = 24 + 2 * (BN / 16);
    constexpr int SPW  = TOT / 8;            // 9 / 5
    constexpr int ABP  = 24 * 1024;
    constexpr int BUF  = ABP + (BN / 16) * 2048;
    constexpr int T    = 16;
    constexpr int WB0  = (MODE == 0) ? 0 : 192;

    __shared__ __align__(16) char lds[2 * BUF];

    int bid = blockIdx.x;
    bid = (bid & 7) * 31 + (bid >> 3);       // bijective XCD swizzle (248=8*31)
    const int mt = bid % 31, nt = bid / 31;  // nt == XCD: one W-panel per XCD L2
    const int m0 = mt * 192, n0 = nt * BN;
    const int tid = threadIdx.x;
    const int w = tid >> 6, l = tid & 63;
    const int ls = l >> 4, lq = l & 15;
    const int wm = w >> 2, wn = w & 3;

    const char* sbase[SPW];
    int ldst[SPW];
    #pragma unroll
    for (int s = 0; s < SPW; ++s) {
        int c = w * SPW + s;
        if (c < 24) {
            int f = c >> 1, sub = c & 1;
            sbase[s] = (const char*)Ag + (size_t)(m0 / 16 + f) * 32768 + sub * 1024;
        } else {
            int cB = c - 24, f = cB >> 1, sub = cB & 1;
            sbase[s] = (const char*)Wg + (size_t)(WB0 + n0 / 16 + f) * 32768 + sub * 1024;
        }
        ldst[s] = c * 1024;
    }
    const int l16 = l * 16;
    auto STG = [&](int buf, int t2) {
        #pragma unroll
        for (int s = 0; s < SPW; ++s)
            __builtin_amdgcn_global_load_lds((gp1)(sbase[s] + (size_t)t2 * 2048 + l16),
                                             (lp3)(lds + buf * BUF + ldst[s]), 16, 0, 0);
    };

    int aoA[MI], aoB[NF];
    #pragma unroll
    for (int i = 0; i < MI; ++i) {
        int r = wm * 96 + i * 16 + lq;
        aoA[i] = (r >> 4) * 2048 + (r & 15) * 64 + ((ls ^ ((r >> 1) & 3)) << 4);
    }
    #pragma unroll
    for (int j = 0; j < NF; ++j) {
        int r = wn * (16 * NF) + j * 16 + lq;
        aoB[j] = ABP + (r >> 4) * 2048 + (r & 15) * 64 + ((ls ^ ((r >> 1) & 3)) << 4);
    }

    f32x4 acc[MI][NF] = {};

    STG(0, 0);
    asm volatile("s_waitcnt vmcnt(0)" ::: "memory");
    SBAR();

    #pragma unroll 1
    for (int t = 0; t < T; ++t) {
        const char* cbp = lds + (t & 1) * BUF;
        if (t + 1 < T) STG((t + 1) & 1, t + 1);

        #pragma unroll
        for (int kc = 0; kc < 2; ++kc) {
            f16x8 ah[MI], b[NF];
            #pragma unroll
            for (int i = 0; i < MI; ++i) ah[i] = *(const f16x8*)(cbp + aoA[i] + kc * 1024);
            #pragma unroll
            for (int j = 0; j < NF; ++j) b[j] = *(const f16x8*)(cbp + aoB[j] + kc * 1024);
            __builtin_amdgcn_s_setprio(1);
            #pragma unroll
            for (int i = 0; i < MI; ++i)
                #pragma unroll
                for (int j = 0; j < NF; ++j)
                    acc[i][j] = mfma16(ah[i], b[j], acc[i][j]);
            __builtin_amdgcn_s_setprio(0);
        }

        asm volatile("s_waitcnt vmcnt(0) lgkmcnt(0)" ::: "memory");
        SBAR();
    }

    // C/D layout: col = lane&15 (-> n), row = (lane>>4)*4 + reg (-> m)
    #pragma unroll
    for (int i = 0; i < MI; ++i)
        #pragma unroll
        for (int j = 0; j < NF; ++j) {
            const int mb = m0 + wm * 96 + i * 16 + 4 * ls;
            const int n  = n0 + wn * (16 * NF) + j * 16 + lq;
            if (MODE == 0) {
                const int which = n >> 10, nn = n & 1023;
                const int hh = nn >> 6, dd = nn & 63;
                if (which == 2) {
                    f16x4 vv;
                    #pragma unroll
                    for (int r = 0; r < 4; ++r) vv[r] = (_Float16)(acc[i][j][r] + bv[nn]);
                    *(f16x4*)&vt[((size_t)hh * 64 + dd) * NCTX + mb] = vv;   // d-major
                } else if (which == 0) {
                    #pragma unroll
                    for (int r = 0; r < 4; ++r)
                        qh[((size_t)hh * NCTX + mb + r) * 64 + dd] = (_Float16)(acc[i][j][r] + bq[nn]);
                } else {
                    #pragma unroll
                    for (int r = 0; r < 4; ++r)
                        kh[((size_t)hh * NCTX + mb + r) * 64 + dd] = (_Float16)acc[i][j][r];
                }
            } else {
                #pragma unroll
                for (int r = 0; r < 4; ++r)
                    outp[(size_t)(mb + r) * 1024 + n] = acc[i][j][r] + bo[n];
            }
        }
}

// ---- flash attention (no-max), 4 waves x 32 q-rows per 128-row tile ----
// Block-cooperative double-buffered K/V LDS staging; granule-swizzled reads;
// epilogue writes ctx (single f16) directly in the TILED staged layout.
__global__ __launch_bounds__(256) void attn_kernel(
    const _Float16* __restrict__ qh, const _Float16* __restrict__ kh,
    const _Float16* __restrict__ vt,
    _Float16* __restrict__ Ahc)
{
    __shared__ alignas(16) _Float16 KT[2][64][64];   // [buf][key][d], granule^=(key&7)
    __shared__ alignas(16) _Float16 VT[2][64][64];   // [buf][d][key], granule^=(d&7)
    __shared__ alignas(16) _Float16 P[4][2][16][64];
    const int bid = blockIdx.x;
    const int hd = bid & 15, t = bid >> 4;
    int b = 0;
    while (t >= kQT[b + 1]) ++b;
    const int kbase = kBASE8[b];
    const int L = kLEN[b];
    const int w = threadIdx.x >> 6, l = threadIdx.x & 63;
    const int ls = l >> 4, lq = l & 15;
    const int xm = lq & 7;
    const int q0l = (t - kQT[b]) * 128 + w * 32;
    const bool active = (q0l < L);       // tail waves participate in barriers only
    const int q0 = kbase + q0l;

    const _Float16* kb = kh + (size_t)hd * NCTX * 64;
    const _Float16* vb = vt + (size_t)hd * 64 * NCTX;

    const char* ksrc[2]; const char* vsrc[2]; int sdst[2];
    #pragma unroll
    for (int s = 0; s < 2; ++s) {
        int G = w * 128 + s * 64 + l;
        int row = G >> 3, g = G & 7;
        ksrc[s] = (const char*)(kb + ((size_t)(kbase + row)) * 64 + (size_t)((g ^ (row & 7)) * 8));
        vsrc[s] = (const char*)(vb + (size_t)row * NCTX + kbase + (size_t)((g ^ (row & 7)) * 8));
        sdst[s] = (w * 128 + s * 64) * 16;   // wave-uniform base; HW adds lane*16
    }
    auto STG = [&](int buf, int t2) {
        #pragma unroll
        for (int s = 0; s < 2; ++s)
            __builtin_amdgcn_global_load_lds((gp1)(ksrc[s] + (size_t)t2 * 8192),
                                             (lp3)((char*)&KT[buf][0][0] + sdst[s]), 16, 0, 0);
        #pragma unroll
        for (int s = 0; s < 2; ++s)
            __builtin_amdgcn_global_load_lds((gp1)(vsrc[s] + (size_t)t2 * 128),
                                             (lp3)((char*)&VT[buf][0][0] + sdst[s]), 16, 0, 0);
    };

    f16x8 qf[2][2];
    if (active) {
        #pragma unroll
        for (int qg = 0; qg < 2; ++qg) {
            const _Float16* qp = qh + ((size_t)hd * NCTX + q0 + qg * 16 + lq) * 64 + ls * 8;
            qf[qg][0] = *(const f16x8*)qp;
            qf[qg][1] = *(const f16x8*)(qp + 32);
        }
    }

    f32x4 acc[2][4] = {};
    float lsum[2] = {0.f, 0.f};
    const int nst = L >> 6;

    STG(0, 0);
    #pragma unroll 1
    for (int tt = 0; tt < nst; ++tt) {
        const int buf = tt & 1;
        if (tt + 1 < nst) {
            STG(buf ^ 1, tt + 1);
            asm volatile("s_waitcnt vmcnt(4)" ::: "memory");
        } else {
            asm volatile("s_waitcnt vmcnt(0)" ::: "memory");
        }
        SBAR();    // buf tt staged block-wide; reads pinned below

        if (active) {
            f32x4 s[2][4];
            __builtin_amdgcn_s_setprio(1);
            #pragma unroll
            for (int g = 0; g < 4; ++g) {
                const char* kp = (const char*)&KT[buf][g * 16 + lq][0];
                f16x8 kf0 = *(const f16x8*)(kp + ((ls ^ xm) * 16));
                f16x8 kf1 = *(const f16x8*)(kp + (((ls + 4) ^ xm) * 16));
                #pragma unroll
                for (int qg = 0; qg < 2; ++qg) {
                    f32x4 z = {};
                    z = mfma16(kf0, qf[qg][0], z);
                    z = mfma16(kf1, qf[qg][1], z);
                    s[qg][g] = z;   // S^T: row = key, col = q = lane&15
                }
            }
            __builtin_amdgcn_s_setprio(0);
            #pragma unroll
            for (int qg = 0; qg < 2; ++qg) {
                float tsum = 0.f;
                #pragma unroll
                for (int g = 0; g < 4; ++g) {
                    f16x4 ph;
                    #pragma unroll
                    for (int r = 0; r < 4; ++r) {
                        float pv = __expf(s[qg][g][r] * 0.125f);
                        tsum += pv;
                        ph[r] = (_Float16)pv;
                    }
                    int gi = 2 * g + (ls >> 1);
                    *(f16x4*)&P[w][qg][lq][(((gi ^ (lq & 7)) << 3) | ((ls & 1) << 2))] = ph;
                }
                tsum += __shfl_xor(tsum, 16, 64);
                tsum += __shfl_xor(tsum, 32, 64);
                lsum[qg] += tsum;
            }
            __builtin_amdgcn_s_setprio(1);
            #pragma unroll
            for (int c = 0; c < 2; ++c) {
                f16x8 pf[2];
                #pragma unroll
                for (int qg = 0; qg < 2; ++qg)
                    pf[qg] = *(const f16x8*)&P[w][qg][lq][((4 * c + ls) ^ (lq & 7)) << 3];
                #pragma unroll
                for (int dg = 0; dg < 4; ++dg) {
                    const char* vp = (const char*)&VT[buf][dg * 16 + lq][0];
                    f16x8 vf = *(const f16x8*)(vp + (((c * 4 + ls) ^ xm) * 16));
                    #pragma unroll
                    for (int qg = 0; qg < 2; ++qg)
                        acc[qg][dg] = mfma16(vf, pf[qg], acc[qg][dg]);
                }
            }
            __builtin_amdgcn_s_setprio(0);
        }

        // everyone's LDS reads of buf done before next staging overwrites it
        asm volatile("s_waitcnt lgkmcnt(0)" ::: "memory");
        SBAR();    // next iteration's STG pinned below
    }

    if (active) {
        #pragma unroll
        for (int qg = 0; qg < 2; ++qg) {
            const float inv = 1.f / lsum[qg];
            const int m = q0 + qg * 16 + lq;     // ctx^T col = q = lane&15
            const int bA = m >> 4, rbA = m & 15, xr = (m >> 1) & 3;
            #pragma unroll
            for (int dg = 0; dg < 4; ++dg) {
                const int k  = hd * 64 + dg * 16 + 4 * ls;
                const int tK = k >> 5;
                const int gs = ((k >> 3) & 3) ^ xr;
                const int e  = k & 7;
                f16x4 ch;
                #pragma unroll
                for (int r = 0; r < 4; ++r) ch[r] = (_Float16)(acc[qg][dg][r] * inv);
                *(f16x4*)((char*)Ahc + ((size_t)(bA * 32 + tK)) * 1024 + rbA * 64 + gs * 16 + e * 2) = ch;
            }
        }
    }
}

extern "C" void kernel_launch(void* const* d_in, const int* in_sizes, int n_in,
                              void* d_out, int out_size, void* d_ws, size_t ws_size,
                              hipStream_t stream)
{
    const float* x  = (const float*)d_in[0];
    const float* Wq = (const float*)d_in[1];
    const float* bq = (const float*)d_in[2];
    const float* Wk = (const float*)d_in[3];
    const float* Wv = (const float*)d_in[4];
    const float* bv = (const float*)d_in[5];
    const float* Wo = (const float*)d_in[6];
    const float* bo = (const float*)d_in[7];
    float* out = (float*)d_out;

    char* p = (char*)d_ws;
    _Float16* Ah  = (_Float16*)p; p += (size_t)NCTX * 1024 * 2;   // tiled
    _Float16* Wh  = (_Float16*)p; p += (size_t)4096 * 1024 * 2;   // tiled
    _Float16* qh  = (_Float16*)p; p += (size_t)NHEAD * NCTX * 64 * 2;
    _Float16* kh  = (_Float16*)p; p += (size_t)NHEAD * NCTX * 64 * 2;
    _Float16* vt  = (_Float16*)p; p += (size_t)NHEAD * NCTX * 64 * 2;
    _Float16* Ahc = (_Float16*)p; p += (size_t)NCTX * 1024 * 2;   // tiled

    presplit_all<<<dim3((NABLK * 32 * 64 + NWBLK * 32 * 64) / 256), 256, 0, stream>>>(
        x, Wq, Wk, Wv, Wo, Ah, Wh);
    gemm1p<0><<<dim3(248), 512, 0, stream>>>(Ah, Wh, bq, bv, nullptr,
                                             qh, kh, vt, nullptr);
    attn_kernel<<<dim3(48 * 16), 256, 0, stream>>>(qh, kh, vt, Ahc);
    gemm1p<1><<<dim3(248), 512, 0, stream>>>(Ahc, Wh, nullptr, nullptr, bo,
                                             nullptr, nullptr, nullptr, out);
}